// Round 5
// baseline (468.676 us; speedup 1.0000x reference)
//
#include <hip/hip_runtime.h>
#include <math.h>

#define D_PROJ 8192
#define C_IN   512
#define P_SP   196   // 14*14
#define NBATCH 32
#define NTP    10    // symmetric tile-pairs of a 4x4 tiling
#define NKQ    4     // K quarters (196 = 4*49)
#define LDA    132   // legacy path only

__device__ __constant__ int IT_OF[NTP] = {0,0,0,0,1,1,1,2,2,3};
__device__ __constant__ int JT_OF[NTP] = {0,1,2,3,1,2,3,2,3,3};

// ---------------------------------------------------------------------------
// global -> LDS direct DMA, 16B per lane (LDS dest wave-uniform + lane*16).
// ---------------------------------------------------------------------------
__device__ inline void gload_lds16(const float* gsrc, float* ldst)
{
    __builtin_amdgcn_global_load_lds(
        (const __attribute__((address_space(1))) void*)(gsrc),
        (__attribute__((address_space(3))) void*)(ldst),
        16, 0, 0);
}

// ---------------------------------------------------------------------------
// Count-sketch recovery: each row of S has one nonzero (+-1) at column h[row].
// ---------------------------------------------------------------------------
__global__ __launch_bounds__(256) void extract_sketch(
    const float* __restrict__ S1, const float* __restrict__ S2,
    int* __restrict__ h1, float* __restrict__ s1,
    int* __restrict__ h2, float* __restrict__ s2)
{
    const int row = blockIdx.x;            // 0..1023
    const int r   = row & (C_IN - 1);
    const float* S = (row < C_IN) ? S1 : S2;
    int*   h = (row < C_IN) ? h1 : h2;
    float* s = (row < C_IN) ? s1 : s2;
    const float4* rp = (const float4*)(S + (size_t)r * D_PROJ);
    for (int c = threadIdx.x; c < D_PROJ / 4; c += 256) {
        float4 v = rp[c];
        if (v.x != 0.0f) { h[r] = 4 * c;     s[r] = v.x; }
        if (v.y != 0.0f) { h[r] = 4 * c + 1; s[r] = v.y; }
        if (v.z != 0.0f) { h[r] = 4 * c + 2; s[r] = v.z; }
        if (v.w != 0.0f) { h[r] = 4 * c + 3; s[r] = v.w; }
    }
}

// ---------------------------------------------------------------------------
// x[b][c][p] -> xT[b][p][c]. 64x64 LDS-tiled transpose.
// ---------------------------------------------------------------------------
__global__ __launch_bounds__(256) void transpose_x(
    const float* __restrict__ x, float* __restrict__ xT)
{
    __shared__ float t[64][65];
    const int b  = blockIdx.z;
    const int pt = blockIdx.x;            // p tile 0..3
    const int ct = blockIdx.y;            // c tile 0..7
    const int tx = threadIdx.x & 63;
    const int ty = threadIdx.x >> 6;
    const int p0 = pt * 64, c0 = ct * 64;
    const float* xb  = x  + (size_t)b * C_IN * P_SP;
    float*       xtb = xT + (size_t)b * P_SP * C_IN;

    #pragma unroll
    for (int k = ty; k < 64; k += 4) {
        int p = p0 + tx;
        t[k][tx] = (p < P_SP) ? xb[(size_t)(c0 + k) * P_SP + p] : 0.0f;
    }
    __syncthreads();
    #pragma unroll
    for (int k = ty; k < 64; k += 4) {
        int p = p0 + k;
        if (p < P_SP) xtb[(size_t)p * C_IN + c0 + tx] = t[tx][k];
    }
}

// ---------------------------------------------------------------------------
// Symmetric batched Gram GEMM: G_tile(it,jt) = A_it * A_jt^T for the 10
// tile-pairs it<=jt. Grid = 1280 = 8 XCD-slots x (4 batches x 10 tp x 4 kq).
// Each block: K-quarter of 49 (7 chunks of 7 p-rows), DMA double-buffered
// staging into one contiguous AB buffer (A rows then B rows -> exactly 7
// 1KB global_load_lds per chunk), 8x8 register tile, fp32 atomicAdd of the
// K-partial into G (same-XCD writers).
// LDS = 14.3 KB, __launch_bounds__(256,4) -> 4+ blocks/CU resident.
// ---------------------------------------------------------------------------
__global__ __launch_bounds__(256, 4) void gram_sym(
    const float* __restrict__ xT, float* __restrict__ G)
{
    __shared__ __align__(16) float AB[2][1792];   // [0,896)=A 7x128, [896,1792)=B

    const int tid  = threadIdx.x;
    const int tx   = tid & 15;       // j quad
    const int ty   = tid >> 4;       // i quad
    const int wid  = tid >> 6;
    const int lane = tid & 63;

    const int id  = blockIdx.x;      // 0..1279
    const int xcd = id & 7;
    const int sub = id >> 3;         // 0..159
    const int bb  = sub / 40;
    const int rr  = sub - bb * 40;
    const int tp  = rr >> 2;
    const int kq  = rr & 3;
    const int b   = xcd + 8 * bb;
    const int it  = IT_OF[tp];
    const int jt  = JT_OF[tp];
    const int cbA = it * 128, cbB = jt * 128;

    const float* xb = xT + (size_t)b * P_SP * C_IN;
    const int p0base = kq * 49;

    // Per chunk: 7 DMA instrs cover A(7 rows x 128) then B(7 rows x 128),
    // flattened: instr k covers flat rows {2k, 2k+1} of the 14-row space.
    #define ISSUE_DMA(P0, BUFI) do {                                          \
        for (int k = wid; k < 7; k += 4) {                                    \
            int frow = 2 * k + (lane >> 5);                                   \
            int aSel = frow < 7;                                              \
            int pr   = aSel ? frow : frow - 7;                                \
            int cb_  = aSel ? cbA : cbB;                                      \
            const float* g = xb + (size_t)((P0) + pr) * C_IN + cb_            \
                             + (lane & 31) * 4;                               \
            gload_lds16(g, &AB[BUFI][k * 256]);                               \
        }                                                                     \
    } while (0)

    float acc[8][8];
    #pragma unroll
    for (int r = 0; r < 8; ++r)
        #pragma unroll
        for (int c = 0; c < 8; ++c) acc[r][c] = 0.0f;

    ISSUE_DMA(p0base, 0);
    __syncthreads();                               // chunk 0 ready

    for (int ch = 0; ch < 7; ++ch) {
        const int cur = ch & 1;
        if (ch + 1 < 7) ISSUE_DMA(p0base + (ch + 1) * 7, cur ^ 1);
        #pragma unroll
        for (int pp = 0; pp < 7; ++pp) {
            const float* ap = &AB[cur][pp * 128];
            const float* bp = &AB[cur][896 + pp * 128];
            float4 a0 = *(const float4*)(ap + ty * 4);
            float4 a1 = *(const float4*)(ap + 64 + ty * 4);
            float4 b0 = *(const float4*)(bp + tx * 4);
            float4 b1 = *(const float4*)(bp + 64 + tx * 4);
            float av[8] = {a0.x, a0.y, a0.z, a0.w, a1.x, a1.y, a1.z, a1.w};
            float bv[8] = {b0.x, b0.y, b0.z, b0.w, b1.x, b1.y, b1.z, b1.w};
            #pragma unroll
            for (int r = 0; r < 8; ++r)
                #pragma unroll
                for (int c = 0; c < 8; ++c)
                    acc[r][c] = fmaf(av[r], bv[c], acc[r][c]);
        }
        __syncthreads();
    }
    #undef ISSUE_DMA

    // K-partial merge into the G tile (4 same-XCD writers per element).
    float* gt = G + (size_t)(b * NTP + tp) * (128 * 128);
    #pragma unroll
    for (int r = 0; r < 8; ++r) {
        int i = (r < 4) ? (ty * 4 + r) : (64 + ty * 4 + (r - 4));
        #pragma unroll
        for (int c = 0; c < 8; ++c) {
            int j = (c < 4) ? (tx * 4 + c) : (64 + tx * 4 + (c - 4));
            atomicAdd(&gt[i * 128 + j], acc[r][c]);
        }
    }
}

// ---------------------------------------------------------------------------
// Scatter G tiles through the count-sketch into per-block LDS histograms.
// Grid = 320 (b x tile-pair, XCD-aligned with gram). Off-diagonal tiles emit
// both the (i,j) and mirrored (j,i) contributions.
//   mode 1: private slice at dest[(b*10+tp)*8192]
//   mode 0: atomicAdd into dest[b*8192] (pre-zeroed d_out)
// ---------------------------------------------------------------------------
__global__ __launch_bounds__(256) void scatter_hist(
    const float* __restrict__ G,
    const int* __restrict__ h1, const float* __restrict__ s1,
    const int* __restrict__ h2, const float* __restrict__ s2,
    float* __restrict__ dest, int mode)
{
    __shared__ float hist[D_PROJ];                // 32 KB
    __shared__ int   h1A[128], h2A[128], h1B[128], h2B[128];
    __shared__ float s1A[128], s2A[128], s1B[128], s2B[128];

    const int tid = threadIdx.x;
    const int id  = blockIdx.x;      // 0..319
    const int xcd = id & 7;
    const int sub = id >> 3;         // 0..39
    const int b   = xcd + 8 * (sub / NTP);
    const int tp  = sub % NTP;
    const int it  = IT_OF[tp];
    const int jt  = JT_OF[tp];
    const int diag = (it == jt);

    if (tid < 128) {
        h1A[tid] = h1[it * 128 + tid];  s1A[tid] = s1[it * 128 + tid];
        h2A[tid] = h2[it * 128 + tid];  s2A[tid] = s2[it * 128 + tid];
        h1B[tid] = h1[jt * 128 + tid];  s1B[tid] = s1[jt * 128 + tid];
        h2B[tid] = h2[jt * 128 + tid];  s2B[tid] = s2[jt * 128 + tid];
    }
    for (int k = tid; k < D_PROJ; k += 256) hist[k] = 0.0f;
    __syncthreads();

    const float* gt = G + (size_t)(b * NTP + tp) * (128 * 128);
    for (int n = 0; n < 16; ++n) {
        int idx = n * 1024 + tid * 4;             // element index in tile
        int r   = idx >> 7;                       // row in it-block
        int c0  = idx & 127;                      // col in jt-block
        float4 g = *(const float4*)(gt + idx);
        float gv[4] = {g.x, g.y, g.z, g.w};
        int   hi = h1A[r];
        float si = s1A[r];
        int   h2i = h2A[r];
        float s2i = s2A[r];
        #pragma unroll
        for (int k = 0; k < 4; ++k) {
            int cc = c0 + k;
            int d1 = (hi + h2B[cc]) & (D_PROJ - 1);
            atomicAdd(&hist[d1], si * s2B[cc] * gv[k]);
            if (!diag) {
                int d2 = (h1B[cc] + h2i) & (D_PROJ - 1);
                atomicAdd(&hist[d2], s1B[cc] * s2i * gv[k]);
            }
        }
    }
    __syncthreads();

    if (mode == 1) {
        float* pb = dest + (size_t)(b * NTP + tp) * D_PROJ;
        for (int k = tid * 4; k < D_PROJ; k += 1024)
            *(float4*)(pb + k) = *(const float4*)(hist + k);
    } else {
        float* pb = dest + (size_t)b * D_PROJ;
        for (int k = tid; k < D_PROJ; k += 256) atomicAdd(&pb[k], hist[k]);
    }
}

// ---------------------------------------------------------------------------
__device__ inline float ssqrt_scale(float v, float inv)
{
    float r = sqrtf(fabsf(v) + 1e-8f) * inv;
    return (v > 0.0f) ? r : ((v < 0.0f) ? -r : 0.0f);
}

__global__ __launch_bounds__(256) void finalize_partial(
    const float* __restrict__ partial, float* __restrict__ out, int ns)
{
    const int b   = blockIdx.x;
    const int tid = threadIdx.x;
    const float* base = partial + (size_t)b * ns * D_PROJ;

    float4 acc[8];
    #pragma unroll
    for (int n = 0; n < 8; ++n) acc[n] = make_float4(0.f, 0.f, 0.f, 0.f);

    for (int t = 0; t < ns; ++t) {
        const float* bt = base + (size_t)t * D_PROJ;
        #pragma unroll
        for (int n = 0; n < 8; ++n) {
            float4 v = *(const float4*)(bt + tid * 4 + n * 1024);
            acc[n].x += v.x; acc[n].y += v.y; acc[n].z += v.z; acc[n].w += v.w;
        }
    }

    float s = 0.0f;
    #pragma unroll
    for (int n = 0; n < 8; ++n)
        s += fabsf(acc[n].x) + fabsf(acc[n].y) + fabsf(acc[n].z) + fabsf(acc[n].w);
    #pragma unroll
    for (int off = 32; off > 0; off >>= 1) s += __shfl_down(s, off, 64);
    __shared__ float red[4];
    if ((tid & 63) == 0) red[tid >> 6] = s;
    __syncthreads();
    float total = red[0] + red[1] + red[2] + red[3];
    float inv   = 1.0f / fmaxf(sqrtf(total + (float)D_PROJ * 1e-8f), 1e-12f);

    float* ob = out + (size_t)b * D_PROJ;
    #pragma unroll
    for (int n = 0; n < 8; ++n) {
        const int k = tid * 4 + n * 1024;
        float4 a = acc[n];
        float4 r;
        r.x = ssqrt_scale(a.x, inv);
        r.y = ssqrt_scale(a.y, inv);
        r.z = ssqrt_scale(a.z, inv);
        r.w = ssqrt_scale(a.w, inv);
        *(float4*)(ob + k) = r;
    }
}

__global__ __launch_bounds__(256) void finalize_inplace(float* __restrict__ out)
{
    const int b = blockIdx.x;
    float* p = out + (size_t)b * D_PROJ;
    const int tid = threadIdx.x;

    float s = 0.0f;
    for (int d = tid; d < D_PROJ; d += 256) s += fabsf(p[d]);
    #pragma unroll
    for (int off = 32; off > 0; off >>= 1) s += __shfl_down(s, off, 64);
    __shared__ float red[4];
    if ((tid & 63) == 0) red[tid >> 6] = s;
    __syncthreads();
    float total = red[0] + red[1] + red[2] + red[3];
    float inv   = 1.0f / fmaxf(sqrtf(total + (float)D_PROJ * 1e-8f), 1e-12f);

    for (int d = tid; d < D_PROJ; d += 256) {
        float v = p[d];
        float r = sqrtf(fabsf(v) + 1e-8f) * inv;
        p[d] = (v > 0.0f) ? r : ((v < 0.0f) ? -r : 0.0f);
    }
}

// ---------------------------------------------------------------------------
// Legacy fused fallback (tiny ws): R1-style gram+scatter with d_out atomics.
// ---------------------------------------------------------------------------
__global__ __launch_bounds__(256) void gram_scatter_legacy(
    const float* __restrict__ x,
    const int* __restrict__ h1, const float* __restrict__ s1,
    const int* __restrict__ h2, const float* __restrict__ s2,
    float* __restrict__ pool)
{
    __shared__ float accL[D_PROJ];
    __shared__ __align__(16) float As[14 * LDA];
    __shared__ __align__(16) float Bs[14 * LDA];
    __shared__ int   h1L[128];
    __shared__ float s1L[128];
    __shared__ int   h2L[128];
    __shared__ float s2L[128];

    const int tid = threadIdx.x;
    const int tx  = tid & 15;
    const int ty  = tid >> 4;
    const int id  = blockIdx.x;
    const int xcd = id & 7;
    const int rem = id >> 3;
    const int tile = rem & 15;
    const int b   = xcd + 8 * (rem >> 4);
    const int it  = tile >> 2;
    const int jt  = tile & 3;

    if (tid < 128) {
        h1L[tid] = h1[it * 128 + tid];
        s1L[tid] = s1[it * 128 + tid];
        h2L[tid] = h2[jt * 128 + tid];
        s2L[tid] = s2[jt * 128 + tid];
    }
    for (int k = tid; k < D_PROJ; k += 256) accL[k] = 0.0f;

    const float* xi = x + ((size_t)b * C_IN + it * 128) * P_SP;
    const float* xj = x + ((size_t)b * C_IN + jt * 128) * P_SP;

    float acc[8][8];
    #pragma unroll
    for (int r = 0; r < 8; ++r)
        #pragma unroll
        for (int c = 0; c < 8; ++c) acc[r][c] = 0.0f;

    for (int ch = 0; ch < 14; ++ch) {
        const int p0 = ch * 14;
        __syncthreads();
        #pragma unroll
        for (int e = 0; e < 7; ++e) {
            int idx = e * 256 + tid;
            int il  = idx / 14;
            int pp  = idx - il * 14;
            As[pp * LDA + il] = xi[il * P_SP + p0 + pp];
            Bs[pp * LDA + il] = xj[il * P_SP + p0 + pp];
        }
        __syncthreads();
        #pragma unroll
        for (int pp = 0; pp < 14; ++pp) {
            const float* ap = &As[pp * LDA];
            const float* bp = &Bs[pp * LDA];
            float4 a0 = *(const float4*)(ap + ty * 4);
            float4 a1 = *(const float4*)(ap + 64 + ty * 4);
            float4 b0 = *(const float4*)(bp + tx * 4);
            float4 b1 = *(const float4*)(bp + 64 + tx * 4);
            float av[8] = {a0.x, a0.y, a0.z, a0.w, a1.x, a1.y, a1.z, a1.w};
            float bv[8] = {b0.x, b0.y, b0.z, b0.w, b1.x, b1.y, b1.z, b1.w};
            #pragma unroll
            for (int r = 0; r < 8; ++r)
                #pragma unroll
                for (int c = 0; c < 8; ++c)
                    acc[r][c] = fmaf(av[r], bv[c], acc[r][c]);
        }
    }

    #pragma unroll
    for (int r = 0; r < 8; ++r) {
        int   il = (r < 4) ? (ty * 4 + r) : (64 + ty * 4 + (r - 4));
        int   hA = h1L[il];
        float sA = s1L[il];
        #pragma unroll
        for (int c = 0; c < 8; ++c) {
            int jl = (c < 4) ? (tx * 4 + c) : (64 + tx * 4 + (c - 4));
            int d  = (hA + h2L[jl]) & (D_PROJ - 1);
            atomicAdd(&accL[d], sA * s2L[jl] * acc[r][c]);
        }
    }
    __syncthreads();

    float* pb = pool + (size_t)b * D_PROJ;
    for (int k = tid; k < D_PROJ; k += 256) atomicAdd(&pb[k], accL[k]);
}

// ---------------------------------------------------------------------------
extern "C" void kernel_launch(void* const* d_in, const int* in_sizes, int n_in,
                              void* d_out, int out_size, void* d_ws, size_t ws_size,
                              hipStream_t stream)
{
    const float* x  = (const float*)d_in[0];   // [32, 512, 14, 14]
    const float* S1 = (const float*)d_in[1];   // [512, 8192]
    const float* S2 = (const float*)d_in[2];   // [512, 8192]
    float* out = (float*)d_out;                // [32, 8192]

    char* ws = (char*)d_ws;
    int*   h1 = (int*)(ws);
    float* s1 = (float*)(ws + 2048);
    int*   h2 = (int*)(ws + 4096);
    float* s2 = (float*)(ws + 6144);

    const size_t XT_BYTES = (size_t)NBATCH * P_SP * C_IN * sizeof(float);      // 12.85 MB
    const size_t G_BYTES  = (size_t)NBATCH * NTP * 128 * 128 * sizeof(float);  // 20.97 MB
    const size_t PT_BYTES = (size_t)NBATCH * NTP * D_PROJ * sizeof(float);     // 10.49 MB

    float* xT      = (float*)(ws + 8192);
    float* G       = (float*)(ws + 8192 + XT_BYTES);
    float* partial = (float*)(ws + 8192 + XT_BYTES + G_BYTES);

    extract_sketch<<<1024, 256, 0, stream>>>(S1, S2, h1, s1, h2, s2);

    if (ws_size >= 8192 + XT_BYTES + G_BYTES + PT_BYTES) {
        hipMemsetAsync(G, 0, G_BYTES, stream);
        transpose_x<<<dim3(4, 8, NBATCH), 256, 0, stream>>>(x, xT);
        gram_sym<<<NBATCH * NTP * NKQ, 256, 0, stream>>>(xT, G);
        scatter_hist<<<NBATCH * NTP, 256, 0, stream>>>(G, h1, s1, h2, s2, partial, 1);
        finalize_partial<<<NBATCH, 256, 0, stream>>>(partial, out, NTP);
    } else if (ws_size >= 8192 + XT_BYTES + G_BYTES) {
        hipMemsetAsync(G, 0, G_BYTES, stream);
        hipMemsetAsync(d_out, 0, (size_t)out_size * sizeof(float), stream);
        transpose_x<<<dim3(4, 8, NBATCH), 256, 0, stream>>>(x, xT);
        gram_sym<<<NBATCH * NTP * NKQ, 256, 0, stream>>>(xT, G);
        scatter_hist<<<NBATCH * NTP, 256, 0, stream>>>(G, h1, s1, h2, s2, out, 0);
        finalize_inplace<<<NBATCH, 256, 0, stream>>>(out);
    } else {
        hipMemsetAsync(d_out, 0, (size_t)out_size * sizeof(float), stream);
        gram_scatter_legacy<<<512, 256, 0, stream>>>(x, h1, s1, h2, s2, out);
        finalize_inplace<<<NBATCH, 256, 0, stream>>>(out);
    }
}

// Round 6
// 184.304 us; speedup vs baseline: 2.5430x; 2.5430x over previous
//
#include <hip/hip_runtime.h>
#include <math.h>

#define D_PROJ 8192
#define C_IN   512
#define P_SP   196   // 14*14
#define NBATCH 32
#define NTP64  36    // symmetric tile-pairs of an 8x8 tiling (64-wide blocks)
#define LDA    132   // legacy path only

__device__ __constant__ int IT64[NTP64] = {
    0,0,0,0,0,0,0,0, 1,1,1,1,1,1,1, 2,2,2,2,2,2, 3,3,3,3,3, 4,4,4,4, 5,5,5, 6,6, 7};
__device__ __constant__ int JT64[NTP64] = {
    0,1,2,3,4,5,6,7, 1,2,3,4,5,6,7, 2,3,4,5,6,7, 3,4,5,6,7, 4,5,6,7, 5,6,7, 6,7, 7};

// ---------------------------------------------------------------------------
// global -> LDS direct DMA, 16B per lane (LDS dest wave-uniform + lane*16).
// ---------------------------------------------------------------------------
__device__ inline void gload_lds16(const float* gsrc, float* ldst)
{
    __builtin_amdgcn_global_load_lds(
        (const __attribute__((address_space(1))) void*)(gsrc),
        (__attribute__((address_space(3))) void*)(ldst),
        16, 0, 0);
}

// ---------------------------------------------------------------------------
// Count-sketch recovery: each row of S has one nonzero (+-1) at column h[row].
// ---------------------------------------------------------------------------
__global__ __launch_bounds__(256) void extract_sketch(
    const float* __restrict__ S1, const float* __restrict__ S2,
    int* __restrict__ h1, float* __restrict__ s1,
    int* __restrict__ h2, float* __restrict__ s2)
{
    const int row = blockIdx.x;            // 0..1023
    const int r   = row & (C_IN - 1);
    const float* S = (row < C_IN) ? S1 : S2;
    int*   h = (row < C_IN) ? h1 : h2;
    float* s = (row < C_IN) ? s1 : s2;
    const float4* rp = (const float4*)(S + (size_t)r * D_PROJ);
    for (int c = threadIdx.x; c < D_PROJ / 4; c += 256) {
        float4 v = rp[c];
        if (v.x != 0.0f) { h[r] = 4 * c;     s[r] = v.x; }
        if (v.y != 0.0f) { h[r] = 4 * c + 1; s[r] = v.y; }
        if (v.z != 0.0f) { h[r] = 4 * c + 2; s[r] = v.z; }
        if (v.w != 0.0f) { h[r] = 4 * c + 3; s[r] = v.w; }
    }
}

// ---------------------------------------------------------------------------
// x[b][c][p] -> xT[b][p][c]. 64x64 LDS-tiled transpose.
// ---------------------------------------------------------------------------
__global__ __launch_bounds__(256) void transpose_x(
    const float* __restrict__ x, float* __restrict__ xT)
{
    __shared__ float t[64][65];
    const int b  = blockIdx.z;
    const int pt = blockIdx.x;            // p tile 0..3
    const int ct = blockIdx.y;            // c tile 0..7
    const int tx = threadIdx.x & 63;
    const int ty = threadIdx.x >> 6;
    const int p0 = pt * 64, c0 = ct * 64;
    const float* xb  = x  + (size_t)b * C_IN * P_SP;
    float*       xtb = xT + (size_t)b * P_SP * C_IN;

    #pragma unroll
    for (int k = ty; k < 64; k += 4) {
        int p = p0 + tx;
        t[k][tx] = (p < P_SP) ? xb[(size_t)(c0 + k) * P_SP + p] : 0.0f;
    }
    __syncthreads();
    #pragma unroll
    for (int k = ty; k < 64; k += 4) {
        int p = p0 + k;
        if (p < P_SP) xtb[(size_t)p * C_IN + c0 + tx] = t[tx][k];
    }
}

// ---------------------------------------------------------------------------
// Symmetric Gram, 64x64 tiles, NO atomics: each block owns one (b, tile-pair)
// output tile over the FULL K=196 and writes it with plain float4 stores.
// Grid = 1152 = 8 XCD-slots x (4 batches x 36 tile-pairs) -> 4.5 blocks/CU.
// Per chunk (14 p-rows): 7x 1KB global_load_lds DMA into a contiguous AB
// buffer (A rows 0..13, B rows 14..27), double-buffered, one barrier/chunk.
// 4x4 register tile; a-reads broadcast across 16 lanes, b-reads 2-way (free).
// ---------------------------------------------------------------------------
__global__ __launch_bounds__(256, 6) void gram64(
    const float* __restrict__ xT, float* __restrict__ G)
{
    __shared__ __align__(16) float AB[2][28 * 64];   // 7 KB per buffer

    const int tid  = threadIdx.x;
    const int tx   = tid & 15;       // j quad (0..15)
    const int ty   = tid >> 4;       // i quad (0..15)
    const int wid  = tid >> 6;
    const int lane = tid & 63;

    const int id  = blockIdx.x;      // 0..1151
    const int xcd = id & 7;
    const int sub = id >> 3;         // 0..143
    const int b   = xcd + 8 * (sub / NTP64);
    const int t   = sub % NTP64;
    const int it  = IT64[t];
    const int jt  = JT64[t];
    const int cbA = it * 64, cbB = jt * 64;

    const float* xb = xT + (size_t)b * P_SP * C_IN;

    // 7 DMA instrs/chunk: instr k covers flat rows 4k..4k+3 of the 28-row
    // space (A p-rows 0..13, then B p-rows 0..13). Global src per-lane.
    #define ISSUE(P0, BUF) do {                                               \
        for (int k = wid; k < 7; k += 4) {                                    \
            int fr   = 4 * k + (lane >> 4);                                   \
            int aSel = fr < 14;                                               \
            int pr   = aSel ? fr : fr - 14;                                   \
            int cb_  = aSel ? cbA : cbB;                                      \
            const float* g = xb + (size_t)((P0) + pr) * C_IN + cb_            \
                             + (lane & 15) * 4;                               \
            gload_lds16(g, &AB[BUF][k * 256]);                                \
        }                                                                     \
    } while (0)

    float acc[4][4];
    #pragma unroll
    for (int r = 0; r < 4; ++r)
        #pragma unroll
        for (int c = 0; c < 4; ++c) acc[r][c] = 0.0f;

    ISSUE(0, 0);
    __syncthreads();                               // chunk 0 ready

    for (int ch = 0; ch < 14; ++ch) {
        const int cur = ch & 1;
        if (ch + 1 < 14) ISSUE((ch + 1) * 14, cur ^ 1);
        #pragma unroll
        for (int pp = 0; pp < 14; ++pp) {
            float4 a = *(const float4*)(&AB[cur][pp * 64 + ty * 4]);
            float4 v = *(const float4*)(&AB[cur][(14 + pp) * 64 + tx * 4]);
            float av[4] = {a.x, a.y, a.z, a.w};
            float bv[4] = {v.x, v.y, v.z, v.w};
            #pragma unroll
            for (int r = 0; r < 4; ++r)
                #pragma unroll
                for (int c = 0; c < 4; ++c)
                    acc[r][c] = fmaf(av[r], bv[c], acc[r][c]);
        }
        __syncthreads();   // implicit vmcnt(0): next chunk's DMA landed
    }
    #undef ISSUE

    // Plain coalesced tile write — block owns this tile, no atomics.
    float* gt = G + (size_t)(b * NTP64 + t) * 4096;
    #pragma unroll
    for (int r = 0; r < 4; ++r) {
        float4 o = make_float4(acc[r][0], acc[r][1], acc[r][2], acc[r][3]);
        *(float4*)(&gt[(ty * 4 + r) * 64 + tx * 4]) = o;
    }
}

// ---------------------------------------------------------------------------
// Scatter G tiles through the count-sketch into per-block LDS histograms.
// Grid = 256 (8 XCD-slots x 4 batches x 8 groups); group g handles tiles
// t = g, g+8, ... (4-5 tiles). Full sketch params live in LDS (8 KB).
// Off-diagonal tiles also emit the mirrored (j,i) term via G symmetry.
//   mode 1: private slice at dest[(b*8+grp)*8192]
//   mode 0: atomicAdd into dest[b*8192] (pre-zeroed d_out)
// ---------------------------------------------------------------------------
__global__ __launch_bounds__(256) void scatter64(
    const float* __restrict__ G,
    const int* __restrict__ h1, const float* __restrict__ s1,
    const int* __restrict__ h2, const float* __restrict__ s2,
    float* __restrict__ dest, int mode)
{
    __shared__ float hist[D_PROJ];                // 32 KB
    __shared__ int   h1L[C_IN], h2L[C_IN];        // 4 KB
    __shared__ float s1L[C_IN], s2L[C_IN];        // 4 KB

    const int tid = threadIdx.x;
    const int id  = blockIdx.x;      // 0..255
    const int xcd = id & 7;
    const int sub = id >> 3;         // 0..31
    const int b   = xcd + 8 * (sub >> 3);
    const int grp = sub & 7;

    for (int k = tid; k < C_IN; k += 256) {
        h1L[k] = h1[k];  s1L[k] = s1[k];
        h2L[k] = h2[k];  s2L[k] = s2[k];
    }
    for (int k = tid; k < D_PROJ; k += 256) hist[k] = 0.0f;
    __syncthreads();

    for (int t = grp; t < NTP64; t += 8) {
        const int it = IT64[t], jt = JT64[t];
        const int diag = (it == jt);
        const float* gt = G + (size_t)(b * NTP64 + t) * 4096;
        #pragma unroll
        for (int n = 0; n < 4; ++n) {
            int idx = n * 1024 + tid * 4;
            int r   = idx >> 6;
            int c0  = idx & 63;
            float4 g = *(const float4*)(gt + idx);
            float gv[4] = {g.x, g.y, g.z, g.w};
            int   gi  = it * 64 + r;
            int   hA  = h1L[gi];
            float sA  = s1L[gi];
            int   hM  = h2L[gi];          // mirror: row plays the h2 role
            float sM  = s2L[gi];
            #pragma unroll
            for (int k = 0; k < 4; ++k) {
                int gj = jt * 64 + c0 + k;
                int d1 = (hA + h2L[gj]) & (D_PROJ - 1);
                atomicAdd(&hist[d1], sA * s2L[gj] * gv[k]);
                if (!diag) {
                    int d2 = (h1L[gj] + hM) & (D_PROJ - 1);
                    atomicAdd(&hist[d2], s1L[gj] * sM * gv[k]);
                }
            }
        }
    }
    __syncthreads();

    if (mode == 1) {
        float* pb = dest + (size_t)(b * 8 + grp) * D_PROJ;
        for (int k = tid * 4; k < D_PROJ; k += 1024)
            *(float4*)(pb + k) = *(const float4*)(hist + k);
    } else {
        float* pb = dest + (size_t)b * D_PROJ;
        for (int k = tid; k < D_PROJ; k += 256) atomicAdd(&pb[k], hist[k]);
    }
}

// ---------------------------------------------------------------------------
__device__ inline float ssqrt_scale(float v, float inv)
{
    float r = sqrtf(fabsf(v) + 1e-8f) * inv;
    return (v > 0.0f) ? r : ((v < 0.0f) ? -r : 0.0f);
}

__global__ __launch_bounds__(256) void finalize_partial(
    const float* __restrict__ partial, float* __restrict__ out, int ns)
{
    const int b   = blockIdx.x;
    const int tid = threadIdx.x;
    const float* base = partial + (size_t)b * ns * D_PROJ;

    float4 acc[8];
    #pragma unroll
    for (int n = 0; n < 8; ++n) acc[n] = make_float4(0.f, 0.f, 0.f, 0.f);

    for (int t = 0; t < ns; ++t) {
        const float* bt = base + (size_t)t * D_PROJ;
        #pragma unroll
        for (int n = 0; n < 8; ++n) {
            float4 v = *(const float4*)(bt + tid * 4 + n * 1024);
            acc[n].x += v.x; acc[n].y += v.y; acc[n].z += v.z; acc[n].w += v.w;
        }
    }

    float s = 0.0f;
    #pragma unroll
    for (int n = 0; n < 8; ++n)
        s += fabsf(acc[n].x) + fabsf(acc[n].y) + fabsf(acc[n].z) + fabsf(acc[n].w);
    #pragma unroll
    for (int off = 32; off > 0; off >>= 1) s += __shfl_down(s, off, 64);
    __shared__ float red[4];
    if ((tid & 63) == 0) red[tid >> 6] = s;
    __syncthreads();
    float total = red[0] + red[1] + red[2] + red[3];
    float inv   = 1.0f / fmaxf(sqrtf(total + (float)D_PROJ * 1e-8f), 1e-12f);

    float* ob = out + (size_t)b * D_PROJ;
    #pragma unroll
    for (int n = 0; n < 8; ++n) {
        const int k = tid * 4 + n * 1024;
        float4 a = acc[n];
        float4 r;
        r.x = ssqrt_scale(a.x, inv);
        r.y = ssqrt_scale(a.y, inv);
        r.z = ssqrt_scale(a.z, inv);
        r.w = ssqrt_scale(a.w, inv);
        *(float4*)(ob + k) = r;
    }
}

__global__ __launch_bounds__(256) void finalize_inplace(float* __restrict__ out)
{
    const int b = blockIdx.x;
    float* p = out + (size_t)b * D_PROJ;
    const int tid = threadIdx.x;

    float s = 0.0f;
    for (int d = tid; d < D_PROJ; d += 256) s += fabsf(p[d]);
    #pragma unroll
    for (int off = 32; off > 0; off >>= 1) s += __shfl_down(s, off, 64);
    __shared__ float red[4];
    if ((tid & 63) == 0) red[tid >> 6] = s;
    __syncthreads();
    float total = red[0] + red[1] + red[2] + red[3];
    float inv   = 1.0f / fmaxf(sqrtf(total + (float)D_PROJ * 1e-8f), 1e-12f);

    for (int d = tid; d < D_PROJ; d += 256) {
        float v = p[d];
        float r = sqrtf(fabsf(v) + 1e-8f) * inv;
        p[d] = (v > 0.0f) ? r : ((v < 0.0f) ? -r : 0.0f);
    }
}

// ---------------------------------------------------------------------------
// Legacy fused fallback (tiny ws): R1-style gram+scatter with d_out atomics.
// ---------------------------------------------------------------------------
__global__ __launch_bounds__(256) void gram_scatter_legacy(
    const float* __restrict__ x,
    const int* __restrict__ h1, const float* __restrict__ s1,
    const int* __restrict__ h2, const float* __restrict__ s2,
    float* __restrict__ pool)
{
    __shared__ float accL[D_PROJ];
    __shared__ __align__(16) float As[14 * LDA];
    __shared__ __align__(16) float Bs[14 * LDA];
    __shared__ int   h1L[128];
    __shared__ float s1L[128];
    __shared__ int   h2L[128];
    __shared__ float s2L[128];

    const int tid = threadIdx.x;
    const int tx  = tid & 15;
    const int ty  = tid >> 4;
    const int id  = blockIdx.x;
    const int xcd = id & 7;
    const int rem = id >> 3;
    const int tile = rem & 15;
    const int b   = xcd + 8 * (rem >> 4);
    const int it  = tile >> 2;
    const int jt  = tile & 3;

    if (tid < 128) {
        h1L[tid] = h1[it * 128 + tid];
        s1L[tid] = s1[it * 128 + tid];
        h2L[tid] = h2[jt * 128 + tid];
        s2L[tid] = s2[jt * 128 + tid];
    }
    for (int k = tid; k < D_PROJ; k += 256) accL[k] = 0.0f;

    const float* xi = x + ((size_t)b * C_IN + it * 128) * P_SP;
    const float* xj = x + ((size_t)b * C_IN + jt * 128) * P_SP;

    float acc[8][8];
    #pragma unroll
    for (int r = 0; r < 8; ++r)
        #pragma unroll
        for (int c = 0; c < 8; ++c) acc[r][c] = 0.0f;

    for (int ch = 0; ch < 14; ++ch) {
        const int p0 = ch * 14;
        __syncthreads();
        #pragma unroll
        for (int e = 0; e < 7; ++e) {
            int idx = e * 256 + tid;
            int il  = idx / 14;
            int pp  = idx - il * 14;
            As[pp * LDA + il] = xi[il * P_SP + p0 + pp];
            Bs[pp * LDA + il] = xj[il * P_SP + p0 + pp];
        }
        __syncthreads();
        #pragma unroll
        for (int pp = 0; pp < 14; ++pp) {
            const float* ap = &As[pp * LDA];
            const float* bp = &Bs[pp * LDA];
            float4 a0 = *(const float4*)(ap + ty * 4);
            float4 a1 = *(const float4*)(ap + 64 + ty * 4);
            float4 b0 = *(const float4*)(bp + tx * 4);
            float4 b1 = *(const float4*)(bp + 64 + tx * 4);
            float av[8] = {a0.x, a0.y, a0.z, a0.w, a1.x, a1.y, a1.z, a1.w};
            float bv[8] = {b0.x, b0.y, b0.z, b0.w, b1.x, b1.y, b1.z, b1.w};
            #pragma unroll
            for (int r = 0; r < 8; ++r)
                #pragma unroll
                for (int c = 0; c < 8; ++c)
                    acc[r][c] = fmaf(av[r], bv[c], acc[r][c]);
        }
    }

    #pragma unroll
    for (int r = 0; r < 8; ++r) {
        int   il = (r < 4) ? (ty * 4 + r) : (64 + ty * 4 + (r - 4));
        int   hA = h1L[il];
        float sA = s1L[il];
        #pragma unroll
        for (int c = 0; c < 8; ++c) {
            int jl = (c < 4) ? (tx * 4 + c) : (64 + tx * 4 + (c - 4));
            int d  = (hA + h2L[jl]) & (D_PROJ - 1);
            atomicAdd(&accL[d], sA * s2L[jl] * acc[r][c]);
        }
    }
    __syncthreads();

    float* pb = pool + (size_t)b * D_PROJ;
    for (int k = tid; k < D_PROJ; k += 256) atomicAdd(&pb[k], accL[k]);
}

// ---------------------------------------------------------------------------
extern "C" void kernel_launch(void* const* d_in, const int* in_sizes, int n_in,
                              void* d_out, int out_size, void* d_ws, size_t ws_size,
                              hipStream_t stream)
{
    const float* x  = (const float*)d_in[0];   // [32, 512, 14, 14]
    const float* S1 = (const float*)d_in[1];   // [512, 8192]
    const float* S2 = (const float*)d_in[2];   // [512, 8192]
    float* out = (float*)d_out;                // [32, 8192]

    char* ws = (char*)d_ws;
    int*   h1 = (int*)(ws);
    float* s1 = (float*)(ws + 2048);
    int*   h2 = (int*)(ws + 4096);
    float* s2 = (float*)(ws + 6144);

    const size_t XT_BYTES = (size_t)NBATCH * P_SP * C_IN * sizeof(float);       // 12.85 MB
    const size_t G_BYTES  = (size_t)NBATCH * NTP64 * 4096 * sizeof(float);      // 18.87 MB
    const size_t PT_BYTES = (size_t)NBATCH * 8 * D_PROJ * sizeof(float);        //  8.39 MB

    float* xT      = (float*)(ws + 8192);
    float* G       = (float*)(ws + 8192 + XT_BYTES);
    float* partial = (float*)(ws + 8192 + XT_BYTES + G_BYTES);

    extract_sketch<<<1024, 256, 0, stream>>>(S1, S2, h1, s1, h2, s2);

    if (ws_size >= 8192 + XT_BYTES + G_BYTES + PT_BYTES) {
        transpose_x<<<dim3(4, 8, NBATCH), 256, 0, stream>>>(x, xT);
        gram64<<<NBATCH * NTP64, 256, 0, stream>>>(xT, G);
        scatter64<<<256, 256, 0, stream>>>(G, h1, s1, h2, s2, partial, 1);
        finalize_partial<<<NBATCH, 256, 0, stream>>>(partial, out, 8);
    } else if (ws_size >= 8192 + XT_BYTES + G_BYTES) {
        hipMemsetAsync(d_out, 0, (size_t)out_size * sizeof(float), stream);
        transpose_x<<<dim3(4, 8, NBATCH), 256, 0, stream>>>(x, xT);
        gram64<<<NBATCH * NTP64, 256, 0, stream>>>(xT, G);
        scatter64<<<256, 256, 0, stream>>>(G, h1, s1, h2, s2, out, 0);
        finalize_inplace<<<NBATCH, 256, 0, stream>>>(out);
    } else {
        hipMemsetAsync(d_out, 0, (size_t)out_size * sizeof(float), stream);
        gram_scatter_legacy<<<512, 256, 0, stream>>>(x, h1, s1, h2, s2, out);
        finalize_inplace<<<NBATCH, 256, 0, stream>>>(out);
    }
}